// Round 4
// baseline (90.760 us; speedup 1.0000x reference)
//
#include <hip/hip_runtime.h>
#include <hip/hip_bf16.h>
#include <math.h>

#define N_SUBWORDS 8192
#define N_WORDS    6000
#define HIDDEN     1024

// One WAVE per word. Lane l owns float4 chunks {l + 64j : j=0..3} of the
// 1024-dim row (4 KB row = 256 float4 = 64 lanes x 4 chunks, coalesced).
//
// Fast path (~2/3 of words): span length == 1 -> softmax over one element is
// identically 1, so out[w] = hs[s0]. Pure copy: no w-load, no dot, no
// shuffle reduce, no exp. Branch is wave-uniform (span bounds are per-word).
//
// General path, per span element:
//   1. load row fragment h[4] (4x float4)
//   2. partial dot with in-register w fragment, 6-step shfl_xor butterfly
//      reduce -> every lane holds the full score. No LDS, no barriers.
//   3. online-softmax update of acc[4], reusing h from registers.
// Epilogue: acc * (1/l) -> out row.
__global__ __launch_bounds__(256) void coref_fused_wave_kernel(
    const float* __restrict__ hs,      // [N_SUBWORDS, HIDDEN]
    const int*   __restrict__ starts,  // [N_WORDS]
    const int*   __restrict__ ends,    // [N_WORDS] inclusive
    const float* __restrict__ w_attn,  // [HIDDEN]
    const float* __restrict__ b_attn,  // [1]
    float*       __restrict__ out)     // [N_WORDS, HIDDEN]
{
    const int tid  = threadIdx.x;
    const int lane = tid & 63;
    const int w    = blockIdx.x * 4 + (tid >> 6);   // wave id -> word
    if (w >= N_WORDS) return;

    const int s0 = starts[w];
    const int s1 = ends[w];   // inclusive, >= s0

    float4* __restrict__ orow = (float4*)(out + (size_t)w * HIDDEN);

    if (s0 == s1) {
        // Single-subword span: attention weight is exactly 1. Copy the row.
        const float4* __restrict__ row = (const float4*)(hs + (size_t)s0 * HIDDEN);
#pragma unroll
        for (int j = 0; j < 4; ++j)
            orow[lane + 64 * j] = row[lane + 64 * j];
        return;
    }

    const float4* __restrict__ wvp = (const float4*)w_attn;
    float4 wv[4];
#pragma unroll
    for (int j = 0; j < 4; ++j)
        wv[j] = wvp[lane + 64 * j];
    const float b = b_attn[0];

    float  m = 0.f, l = 1.f;
    float4 acc[4];

    for (int s = s0; s <= s1; ++s) {
        const float4* __restrict__ row = (const float4*)(hs + (size_t)s * HIDDEN);
        float4 h[4];
#pragma unroll
        for (int j = 0; j < 4; ++j)
            h[j] = row[lane + 64 * j];

        float part = 0.f;
#pragma unroll
        for (int j = 0; j < 4; ++j)
            part += h[j].x * wv[j].x + h[j].y * wv[j].y +
                    h[j].z * wv[j].z + h[j].w * wv[j].w;

        // wave-64 butterfly: every lane ends with the full sum
#pragma unroll
        for (int off = 32; off > 0; off >>= 1)
            part += __shfl_xor(part, off, 64);

        const float score = part + b;

        if (s == s0) {
            m = score;
            l = 1.f;
#pragma unroll
            for (int j = 0; j < 4; ++j)
                acc[j] = h[j];
        } else {
            const float mn    = fmaxf(m, score);
            const float alpha = __expf(m - mn);      // rescale old state
            const float p     = __expf(score - mn);  // new element weight
            m = mn;
            l = l * alpha + p;
#pragma unroll
            for (int j = 0; j < 4; ++j) {
                acc[j].x = acc[j].x * alpha + p * h[j].x;
                acc[j].y = acc[j].y * alpha + p * h[j].y;
                acc[j].z = acc[j].z * alpha + p * h[j].z;
                acc[j].w = acc[j].w * alpha + p * h[j].w;
            }
        }
    }

    const float inv_l = 1.f / l;
#pragma unroll
    for (int j = 0; j < 4; ++j) {
        float4 o;
        o.x = acc[j].x * inv_l;
        o.y = acc[j].y * inv_l;
        o.z = acc[j].z * inv_l;
        o.w = acc[j].w * inv_l;
        orow[lane + 64 * j] = o;
    }
}

extern "C" void kernel_launch(void* const* d_in, const int* in_sizes, int n_in,
                              void* d_out, int out_size, void* d_ws, size_t ws_size,
                              hipStream_t stream) {
    const float* hs     = (const float*)d_in[0];  // [8192*1024] f32
    const int*   starts = (const int*)d_in[1];    // [6000]
    const int*   ends   = (const int*)d_in[2];    // [6000]
    const float* w_attn = (const float*)d_in[3];  // [1024] f32
    const float* b_attn = (const float*)d_in[4];  // [1] f32
    float*       out    = (float*)d_out;          // [6000*1024] f32

    // 6000 words, one wave each, 4 waves per 256-thread block -> 1500 blocks
    coref_fused_wave_kernel<<<dim3((N_WORDS + 3) / 4), dim3(256), 0, stream>>>(
        hs, starts, ends, w_attn, b_attn, out);
}